// Round 1
// baseline (11041.098 us; speedup 1.0000x reference)
//
#include <hip/hip_runtime.h>
#include <stdint.h>

#define NTOT    131072
#define NSTEP   60
#define MBLK    128
#define PLANE_H 16384          // halves per fragment plane (32 groups * 64 slots * 8)
#define IMG_H   32768          // halves per image (hi + lo plane)
#define IMG_B   65536          // bytes per image

// LDS byte offsets — no W slab anymore: A-operand streams from L2 (frag-order
// weight images are 384 KB total, fully L2-resident). 73 KB/block -> 2 blocks/CU.
#define OFF_ACT  0             // 65536: ACT image (frag order, hi + lo)
#define OFF_GP   65536         // 4*128*2*4 = 4096
#define OFF_W1C  69632         // 2048
#define OFF_B2   71680         // 512
#define OFF_B3   72192
#define OFF_B4   72704
#define OFF_W5   73216
#define OFF_XB   73728         // 256*4 = 1024
#define LDS_TOTAL 74752

typedef float  f32x4  __attribute__((ext_vector_type(4)));
typedef float  f32x16 __attribute__((ext_vector_type(16)));
typedef short  bf16x8 __attribute__((ext_vector_type(8)));
union FragU { bf16x8 v; uint32_t u[4]; uint16_t h[8]; };

static __device__ __forceinline__ uint32_t rne_bits(float f) {
  uint32_t u = __float_as_uint(f);
  return u + 0x7fffu + ((u >> 16) & 1u);   // high16 = rne bf16
}
static __device__ __forceinline__ float fsigm(float z) {
  return __builtin_amdgcn_rcpf(1.0f + __builtin_amdgcn_exp2f(z * -1.44269504089f));
}
// dst.lo = bf16_rne(a), dst.hi = bf16_rne(b) — 1 instr replaces rne_bits+perm pair
static __device__ __forceinline__ uint32_t cvt_pk_bf16(float a, float b) {
  uint32_t r;
  asm("v_cvt_pk_bf16_f32 %0, %1, %2" : "=v"(r) : "v"(a), "v"(b));
  return r;
}

// ---- prep: 6 fragment-order (32x32x16 A-layout) split-bf16 W images ----
// img 0..2: forward A = W^T of w2,w3,w4 (m=out, k=in)
// img 3..5: backward A = W natural of w4,w3,w2 (m=in, k=out)
extern "C" __global__ void ebm_prep_kernel(const float* __restrict__ w2,
                                           const float* __restrict__ w3,
                                           const float* __restrict__ w4,
                                           uint16_t* __restrict__ ws) {
  int img = blockIdx.x;
  bool bwd = img >= 3;
  int li = bwd ? 5 - img : img;
  const float* w = (li == 0) ? w2 : (li == 1) ? w3 : w4;
  uint16_t* hiP = ws + (size_t)img * IMG_H;
  uint16_t* loP = hiP + PLANE_H;
  for (int e = threadIdx.x; e < 16384; e += blockDim.x) {
    int i = e >> 7, o = e & 127;            // w[i][o]
    int m = bwd ? i : o;
    int k = bwd ? o : i;
    int slot = ((m >> 5) * 8 + (k >> 4)) * 64 + (m & 31) + 32 * ((k >> 3) & 1);
    int off = slot * 8 + (k & 7);
    float v = w[e];
    uint32_t tb = rne_bits(v);
    float lo = v - __uint_as_float(tb & 0xffff0000u);
    hiP[off] = (uint16_t)(tb >> 16);
    loP[off] = (uint16_t)(rne_bits(lo) >> 16);
  }
}

extern "C" __global__ void __launch_bounds__(512, 4)
ebm_mcmc_kernel(const float* __restrict__ x0, const float* __restrict__ w1,
                const float* __restrict__ b1, const float* __restrict__ b2,
                const float* __restrict__ b3, const float* __restrict__ b4,
                const float* __restrict__ w5, const float* __restrict__ noise,
                const uint16_t* __restrict__ wsW, float* __restrict__ out)
{
  extern __shared__ char smem[];
  uint16_t* ACTH  = (uint16_t*)(smem + OFF_ACT);    // ACT frag image, lo at +PLANE_H
  float*    GPf   = (float*)(smem + OFF_GP);        // [wr][128 samples][2]
  f32x4*    W1C   = (f32x4*)(smem + OFF_W1C);       // (w1[0][n], w1[1][n], b1[n], 0)
  float*    B2s   = (float*)(smem + OFF_B2);
  float*    B3s   = (float*)(smem + OFF_B3);
  float*    B4s   = (float*)(smem + OFF_B4);
  float*    W5s   = (float*)(smem + OFF_W5);
  float*    XB    = (float*)(smem + OFF_XB);        // x state fp32 [128][2]

  const int t   = threadIdx.x;
  const int blk = blockIdx.x;

  if (t < 128) {
    f32x4 v; v.x = w1[t]; v.y = w1[128 + t]; v.z = b1[t]; v.w = 0.0f;
    W1C[t] = v;
    B2s[t] = b2[t]; B3s[t] = b3[t]; B4s[t] = b4[t]; W5s[t] = w5[t];
  }
  if (t < 256) XB[t] = x0[blk * 256 + t];

  const int lane = t & 63;
  const int wave = t >> 6;
  const int c32 = lane & 31;      // sample within 32-tile / A-row m
  const int h   = lane >> 5;      // lane half (k-half of frags; row offset 4h in C)
  const int wr  = wave & 3;       // hidden rows 32*wr..+31
  const int wsh = wave >> 2;      // sample half: samples 64*wsh..+63

  size_t nbase = (size_t)blk * 256 + (t & 255);
  float nz = (t < 256) ? noise[nbase] : 0.0f;

  __syncthreads();

  f32x16 acc[2];                  // [sample tile b], 16 regs each
  float D1[32], D2[32], D3[32];   // silu' fp32, [b*16 + r]

  // A-frags stream straight from L2: frag offset ((wr*8+ks)*64+lane)*8 halves
  auto gemm = [&](int img) {
    const uint16_t* ab = wsW + (size_t)img * IMG_H + (size_t)(wr * 4096 + lane * 8);
    acc[0] = (f32x16)0.0f; acc[1] = (f32x16)0.0f;
#pragma unroll
    for (int ks = 0; ks < 8; ++ks) {
      FragU Ah, Al;
      Ah.v = *(const bf16x8*)(ab + ks * 512);
      Al.v = *(const bf16x8*)(ab + ks * 512 + PLANE_H);
      const uint16_t* bp0 = ACTH + (((2 * wsh + 0) * 8 + ks) * 64 + lane) * 8;
      const uint16_t* bp1 = ACTH + (((2 * wsh + 1) * 8 + ks) * 64 + lane) * 8;
      FragU B0h, B0l, B1h, B1l;
      B0h.v = *(const bf16x8*)bp0;  B0l.v = *(const bf16x8*)(bp0 + PLANE_H);
      B1h.v = *(const bf16x8*)bp1;  B1l.v = *(const bf16x8*)(bp1 + PLANE_H);
      acc[0] = __builtin_amdgcn_mfma_f32_32x32x16_bf16(Ah.v, B0h.v, acc[0], 0, 0, 0);
      acc[1] = __builtin_amdgcn_mfma_f32_32x32x16_bf16(Ah.v, B1h.v, acc[1], 0, 0, 0);
      acc[0] = __builtin_amdgcn_mfma_f32_32x32x16_bf16(Ah.v, B0l.v, acc[0], 0, 0, 0);
      acc[1] = __builtin_amdgcn_mfma_f32_32x32x16_bf16(Ah.v, B1l.v, acc[1], 0, 0, 0);
      acc[0] = __builtin_amdgcn_mfma_f32_32x32x16_bf16(Al.v, B0h.v, acc[0], 0, 0, 0);
      acc[1] = __builtin_amdgcn_mfma_f32_32x32x16_bf16(Al.v, B1h.v, acc[1], 0, 0, 0);
    }
  };

  // C element (b, t, rr) -> B-frag image: k = 32wr+8t+4h+rr, n = 64wsh+32b+c32
  auto storeAct = [&](int b, int tt, f32x4 v) {
    uint32_t h01 = cvt_pk_bf16(v[0], v[1]);
    uint32_t h23 = cvt_pk_bf16(v[2], v[3]);
    float r0 = v[0] - __uint_as_float(h01 << 16);
    float r1 = v[1] - __uint_as_float(h01 & 0xffff0000u);
    float r2 = v[2] - __uint_as_float(h23 << 16);
    float r3 = v[3] - __uint_as_float(h23 & 0xffff0000u);
    int slot = ((2 * wsh + b) * 8 + 2 * wr + (tt >> 1)) * 64 + c32 + 32 * (tt & 1);
    uint16_t* p = ACTH + slot * 8 + 4 * h;
    *(uint2*)p = make_uint2(h01, h23);
    *(uint2*)(p + PLANE_H) = make_uint2(cvt_pk_bf16(r0, r1), cvt_pk_bf16(r2, r3));
  };

  auto ep_fwd = [&](const float* Bs, float* D) {
#pragma unroll
    for (int tt = 0; tt < 4; ++tt) {
      f32x4 bv = *(const f32x4*)(Bs + 32 * wr + 8 * tt + 4 * h);
#pragma unroll
      for (int b = 0; b < 2; ++b) {
        f32x4 hv;
#pragma unroll
        for (int rr = 0; rr < 4; ++rr) {
          float z = acc[b][4 * tt + rr] + bv[rr];
          float s = fsigm(z);
          float hh = z * s;
          D[b * 16 + 4 * tt + rr] = s * (1.0f + z - hh);
          hv[rr] = hh;
        }
        storeAct(b, tt, hv);
      }
    }
  };

  auto ep_v4 = [&]() {
#pragma unroll
    for (int tt = 0; tt < 4; ++tt) {
      f32x4 bv = *(const f32x4*)(B4s + 32 * wr + 8 * tt + 4 * h);
      f32x4 wv = *(const f32x4*)(W5s + 32 * wr + 8 * tt + 4 * h);
#pragma unroll
      for (int b = 0; b < 2; ++b) {
        f32x4 vv;
#pragma unroll
        for (int rr = 0; rr < 4; ++rr) {
          float z = acc[b][4 * tt + rr] + bv[rr];
          float s = fsigm(z);
          vv[rr] = wv[rr] * (s * (1.0f + z - z * s));
        }
        storeAct(b, tt, vv);
      }
    }
  };

  auto ep_bwd = [&](float* D) {
#pragma unroll
    for (int tt = 0; tt < 4; ++tt)
#pragma unroll
      for (int b = 0; b < 2; ++b) {
        f32x4 vv;
#pragma unroll
        for (int rr = 0; rr < 4; ++rr)
          vv[rr] = acc[b][4 * tt + rr] * D[b * 16 + 4 * tt + rr];
        storeAct(b, tt, vv);
      }
  };

  // u1 epilogue: v1 = acc .* D1 ; in-register contraction against w1 -> GP
  auto ep_bwd1 = [&]() {
    float gx[2] = {0.f, 0.f}, gy[2] = {0.f, 0.f};
#pragma unroll
    for (int tt = 0; tt < 4; ++tt) {
      const f32x4* wp = W1C + 32 * wr + 8 * tt + 4 * h;
      f32x4 w0 = wp[0], w1v = wp[1], w2v = wp[2], w3v = wp[3];
#pragma unroll
      for (int b = 0; b < 2; ++b) {
        float v0 = acc[b][4 * tt + 0] * D1[b * 16 + 4 * tt + 0];
        float v1 = acc[b][4 * tt + 1] * D1[b * 16 + 4 * tt + 1];
        float v2 = acc[b][4 * tt + 2] * D1[b * 16 + 4 * tt + 2];
        float v3 = acc[b][4 * tt + 3] * D1[b * 16 + 4 * tt + 3];
        gx[b] = fmaf(v0, w0.x, fmaf(v1, w1v.x, fmaf(v2, w2v.x, fmaf(v3, w3v.x, gx[b]))));
        gy[b] = fmaf(v0, w0.y, fmaf(v1, w1v.y, fmaf(v2, w2v.y, fmaf(v3, w3v.y, gy[b]))));
      }
    }
#pragma unroll
    for (int b = 0; b < 2; ++b) {
      gx[b] += __shfl_xor(gx[b], 32);
      gy[b] += __shfl_xor(gy[b], 32);
      if (h == 0) {
        int s = 64 * wsh + 32 * b + c32;
        *(float2*)(GPf + (wr * 128 + s) * 2) = make_float2(gx[b], gy[b]);
      }
    }
  };

  auto l1_phase = [&]() {
    float2 xv[2];
#pragma unroll
    for (int b = 0; b < 2; ++b)
      xv[b] = *(const float2*)(XB + 2 * (64 * wsh + 32 * b + c32));
#pragma unroll
    for (int tt = 0; tt < 4; ++tt) {
      const f32x4* wp = W1C + 32 * wr + 8 * tt + 4 * h;
      f32x4 wvs0 = wp[0], wvs1 = wp[1], wvs2 = wp[2], wvs3 = wp[3];
#pragma unroll
      for (int b = 0; b < 2; ++b) {
        f32x4 hv;
        f32x4 wv_[4] = {wvs0, wvs1, wvs2, wvs3};
#pragma unroll
        for (int rr = 0; rr < 4; ++rr) {
          float z = fmaf(xv[b].x, wv_[rr].x, fmaf(xv[b].y, wv_[rr].y, wv_[rr].z));
          float s = fsigm(z);
          float hh = z * s;
          D1[b * 16 + 4 * tt + rr] = s * (1.0f + z - hh);
          hv[rr] = hh;
        }
        storeAct(b, tt, hv);
      }
    }
  };

  auto g_finish = [&](int step) {
    if (t < 256) {
      int s = t >> 1, p = t & 1;
      float g = GPf[s * 2 + p] + GPf[256 + s * 2 + p] +
                GPf[512 + s * 2 + p] + GPf[768 + s * 2 + p];
      g = fminf(fmaxf(g, -0.03f), 0.03f);
      float epsv = 10.0f * (1.0f - (float)step / 60.0f);
      float xn = XB[t] + sqrtf(2.0f * epsv) * nz * 0.005f + epsv * g;
      xn = fminf(fmaxf(xn, -2.43f), 3.05f);
      XB[t] = xn;
      if (step == NSTEP - 1) {
        out[(size_t)blk * 256 + t] = xn;
      } else {
        nz = noise[(size_t)(step + 1) * NTOT * 2 + nbase];
      }
    }
  };

#pragma unroll 1
  for (int step = 0; step < NSTEP; ++step) {
    l1_phase();        __syncthreads();
    gemm(0);           __syncthreads();   // z2 (A = W2^T from L2)
    ep_fwd(B2s, D2);   __syncthreads();
    gemm(1);           __syncthreads();   // z3
    ep_fwd(B3s, D3);   __syncthreads();
    gemm(2);           __syncthreads();   // z4
    ep_v4();           __syncthreads();
    gemm(3);           __syncthreads();   // u3 (A = W4 nat)
    ep_bwd(D3);        __syncthreads();
    gemm(4);           __syncthreads();   // u2
    ep_bwd(D2);        __syncthreads();
    gemm(5);           __syncthreads();   // u1
    ep_bwd1();         __syncthreads();   // g partials
    g_finish(step);    __syncthreads();
  }
}

extern "C" void kernel_launch(void* const* d_in, const int* in_sizes, int n_in,
                              void* d_out, int out_size, void* d_ws, size_t ws_size,
                              hipStream_t stream) {
  // inputs: x0,w1,b1,w2,b2,w3,b3,w4,b4,w5,b5,noise
  (void)in_sizes; (void)n_in; (void)out_size; (void)ws_size;
  hipFuncSetAttribute((const void*)ebm_mcmc_kernel,
                      hipFuncAttributeMaxDynamicSharedMemorySize, LDS_TOTAL);
  ebm_prep_kernel<<<6, 256, 0, stream>>>(
      (const float*)d_in[3], (const float*)d_in[5], (const float*)d_in[7],
      (uint16_t*)d_ws);
  ebm_mcmc_kernel<<<NTOT / MBLK, 512, LDS_TOTAL, stream>>>(
      (const float*)d_in[0], (const float*)d_in[1], (const float*)d_in[2],
      (const float*)d_in[4], (const float*)d_in[6], (const float*)d_in[8],
      (const float*)d_in[9], (const float*)d_in[11], (const uint16_t*)d_ws,
      (float*)d_out);
}

// Round 2
// 5882.371 us; speedup vs baseline: 1.8770x; 1.8770x over previous
//
#include <hip/hip_runtime.h>
#include <stdint.h>

#define NTOT    131072
#define NSTEP   60
#define SBLK    64             // samples per block (halved: register relief)
#define NBLK    (NTOT / SBLK)  // 2048 blocks
#define PLANE_H 16384          // halves per A-image plane (128x128 frag order)
#define IMG_H   32768          // halves per A image (hi + lo plane)
#define BPLANE_H 8192          // halves per ACT plane (128k x 64n frag order)

// LDS byte offsets — 39.4 KB/block -> LDS allows 4 blocks/CU; VGPR cap (128
// under launch_bounds(512,2) = min 2 blocks/CU, CUDA semantics per r1
// evidence VGPR=64 at arg 4) allows 2 blocks/CU = 16 waves.
#define OFF_ACT  0             // 32768: ACT image (frag order, hi + lo)
#define OFF_GP   32768         // 4*64*2*4 = 2048
#define OFF_W1C  34816         // 2048
#define OFF_B2   36864         // 512
#define OFF_B3   37376
#define OFF_B4   37888
#define OFF_W5   38400
#define OFF_XB   38912         // 64*2*4 = 512
#define LDS_TOTAL 39424

typedef float  f32x4  __attribute__((ext_vector_type(4)));
typedef float  f32x16 __attribute__((ext_vector_type(16)));
typedef short  bf16x8 __attribute__((ext_vector_type(8)));
union FragU { bf16x8 v; uint32_t u[4]; uint16_t h[8]; };

static __device__ __forceinline__ uint32_t rne_bits(float f) {
  uint32_t u = __float_as_uint(f);
  return u + 0x7fffu + ((u >> 16) & 1u);   // high16 = rne bf16
}
static __device__ __forceinline__ float fsigm(float z) {
  return __builtin_amdgcn_rcpf(1.0f + __builtin_amdgcn_exp2f(z * -1.44269504089f));
}
// dst.lo = bf16_rne(a), dst.hi = bf16_rne(b)
static __device__ __forceinline__ uint32_t cvt_pk_bf16(float a, float b) {
  uint32_t r;
  asm("v_cvt_pk_bf16_f32 %0, %1, %2" : "=v"(r) : "v"(a), "v"(b));
  return r;
}

// ---- prep: 6 fragment-order (32x32x16 A-layout) split-bf16 W images ----
// img 0..2: forward A = W^T of w2,w3,w4 (m=out, k=in)
// img 3..5: backward A = W natural of w4,w3,w2 (m=in, k=out)
extern "C" __global__ void ebm_prep_kernel(const float* __restrict__ w2,
                                           const float* __restrict__ w3,
                                           const float* __restrict__ w4,
                                           uint16_t* __restrict__ ws) {
  int img = blockIdx.x;
  bool bwd = img >= 3;
  int li = bwd ? 5 - img : img;
  const float* w = (li == 0) ? w2 : (li == 1) ? w3 : w4;
  uint16_t* hiP = ws + (size_t)img * IMG_H;
  uint16_t* loP = hiP + PLANE_H;
  for (int e = threadIdx.x; e < 16384; e += blockDim.x) {
    int i = e >> 7, o = e & 127;            // w[i][o]
    int m = bwd ? i : o;
    int k = bwd ? o : i;
    int slot = ((m >> 5) * 8 + (k >> 4)) * 64 + (m & 31) + 32 * ((k >> 3) & 1);
    int off = slot * 8 + (k & 7);
    float v = w[e];
    uint32_t tb = rne_bits(v);
    float lo = v - __uint_as_float(tb & 0xffff0000u);
    hiP[off] = (uint16_t)(tb >> 16);
    loP[off] = (uint16_t)(rne_bits(lo) >> 16);
  }
}

extern "C" __global__ void __launch_bounds__(512, 2)
ebm_mcmc_kernel(const float* __restrict__ x0, const float* __restrict__ w1,
                const float* __restrict__ b1, const float* __restrict__ b2,
                const float* __restrict__ b3, const float* __restrict__ b4,
                const float* __restrict__ w5, const float* __restrict__ noise,
                const uint16_t* __restrict__ wsW, float* __restrict__ out)
{
  extern __shared__ char smem[];
  uint16_t* ACTH  = (uint16_t*)(smem + OFF_ACT);    // ACT frag image, lo at +BPLANE_H
  float*    GPf   = (float*)(smem + OFF_GP);        // [wr][64 samples][2]
  f32x4*    W1C   = (f32x4*)(smem + OFF_W1C);       // (w1[0][n], w1[1][n], b1[n], 0)
  float*    B2s   = (float*)(smem + OFF_B2);
  float*    B3s   = (float*)(smem + OFF_B3);
  float*    B4s   = (float*)(smem + OFF_B4);
  float*    W5s   = (float*)(smem + OFF_W5);
  float*    XB    = (float*)(smem + OFF_XB);        // x state fp32 [64][2]

  const int t   = threadIdx.x;
  const int blk = blockIdx.x;

  if (t < 128) {
    f32x4 v; v.x = w1[t]; v.y = w1[128 + t]; v.z = b1[t]; v.w = 0.0f;
    W1C[t] = v;
    B2s[t] = b2[t]; B3s[t] = b3[t]; B4s[t] = b4[t]; W5s[t] = w5[t];
    XB[t] = x0[(size_t)blk * 128 + t];
  }

  const int lane = t & 63;
  const int wave = t >> 6;
  const int c32 = lane & 31;      // sample within 32-tile / A-row m
  const int h   = lane >> 5;      // lane half (k-half of frags; row offset 4h in C)
  const int wr  = wave & 3;       // hidden rows 32*wr..+31
  const int wsh = wave >> 2;      // sample tile: samples 32*wsh..+31

  size_t nbase = (size_t)blk * 128 + (t & 127);
  float nz = (t < 128) ? noise[nbase] : 0.0f;

  __syncthreads();

  f32x16 acc;                     // one 32x32 C tile per wave pair-slice
  float D1[16], D2[16], D3[16];   // silu' fp32

  // A-frags stream straight from L2 (384 KB image set, L2-resident):
  // frag offset ((wr*8+ks)*64+lane)*8 halves, lo plane at +PLANE_H
  auto gemm = [&](int img) {
    const uint16_t* ab = wsW + (size_t)img * IMG_H + (size_t)(wr * 4096 + lane * 8);
    acc = (f32x16)0.0f;
#pragma unroll
    for (int ks = 0; ks < 8; ++ks) {
      FragU Ah, Al;
      Ah.v = *(const bf16x8*)(ab + ks * 512);
      Al.v = *(const bf16x8*)(ab + ks * 512 + PLANE_H);
      const uint16_t* bp = ACTH + ((wsh * 8 + ks) * 64 + lane) * 8;
      FragU Bh, Bl;
      Bh.v = *(const bf16x8*)bp;
      Bl.v = *(const bf16x8*)(bp + BPLANE_H);
      acc = __builtin_amdgcn_mfma_f32_32x32x16_bf16(Ah.v, Bh.v, acc, 0, 0, 0);
      acc = __builtin_amdgcn_mfma_f32_32x32x16_bf16(Ah.v, Bl.v, acc, 0, 0, 0);
      acc = __builtin_amdgcn_mfma_f32_32x32x16_bf16(Al.v, Bh.v, acc, 0, 0, 0);
    }
  };

  // C element (tt, rr) -> B-frag image: k = 32wr+8tt+4h+rr, n = 32wsh+c32
  auto storeAct = [&](int tt, f32x4 v) {
    uint32_t h01 = cvt_pk_bf16(v[0], v[1]);
    uint32_t h23 = cvt_pk_bf16(v[2], v[3]);
    float r0 = v[0] - __uint_as_float(h01 << 16);
    float r1 = v[1] - __uint_as_float(h01 & 0xffff0000u);
    float r2 = v[2] - __uint_as_float(h23 << 16);
    float r3 = v[3] - __uint_as_float(h23 & 0xffff0000u);
    int slot = (wsh * 8 + 2 * wr + (tt >> 1)) * 64 + c32 + 32 * (tt & 1);
    uint16_t* p = ACTH + slot * 8 + 4 * h;
    *(uint2*)p = make_uint2(h01, h23);
    *(uint2*)(p + BPLANE_H) = make_uint2(cvt_pk_bf16(r0, r1), cvt_pk_bf16(r2, r3));
  };

  auto ep_fwd = [&](const float* Bs, float* D) {
#pragma unroll
    for (int tt = 0; tt < 4; ++tt) {
      f32x4 bv = *(const f32x4*)(Bs + 32 * wr + 8 * tt + 4 * h);
      f32x4 hv;
#pragma unroll
      for (int rr = 0; rr < 4; ++rr) {
        float z = acc[4 * tt + rr] + bv[rr];
        float s = fsigm(z);
        float hh = z * s;
        D[4 * tt + rr] = s * (1.0f + z - hh);
        hv[rr] = hh;
      }
      storeAct(tt, hv);
    }
  };

  auto ep_v4 = [&]() {
#pragma unroll
    for (int tt = 0; tt < 4; ++tt) {
      f32x4 bv = *(const f32x4*)(B4s + 32 * wr + 8 * tt + 4 * h);
      f32x4 wv = *(const f32x4*)(W5s + 32 * wr + 8 * tt + 4 * h);
      f32x4 vv;
#pragma unroll
      for (int rr = 0; rr < 4; ++rr) {
        float z = acc[4 * tt + rr] + bv[rr];
        float s = fsigm(z);
        vv[rr] = wv[rr] * (s * (1.0f + z - z * s));
      }
      storeAct(tt, vv);
    }
  };

  auto ep_bwd = [&](float* D) {
#pragma unroll
    for (int tt = 0; tt < 4; ++tt) {
      f32x4 vv;
#pragma unroll
      for (int rr = 0; rr < 4; ++rr)
        vv[rr] = acc[4 * tt + rr] * D[4 * tt + rr];
      storeAct(tt, vv);
    }
  };

  // u1 epilogue: v1 = acc .* D1 ; in-register contraction against w1 -> GP
  auto ep_bwd1 = [&]() {
    float gx = 0.f, gy = 0.f;
#pragma unroll
    for (int tt = 0; tt < 4; ++tt) {
      const f32x4* wp = W1C + 32 * wr + 8 * tt + 4 * h;
#pragma unroll
      for (int rr = 0; rr < 4; ++rr) {
        f32x4 w = wp[rr];
        float v = acc[4 * tt + rr] * D1[4 * tt + rr];
        gx = fmaf(v, w.x, gx);
        gy = fmaf(v, w.y, gy);
      }
    }
    gx += __shfl_xor(gx, 32);
    gy += __shfl_xor(gy, 32);
    if (h == 0) {
      int s = 32 * wsh + c32;
      *(float2*)(GPf + (wr * 64 + s) * 2) = make_float2(gx, gy);
    }
  };

  auto l1_phase = [&]() {
    float2 xv = *(const float2*)(XB + 2 * (32 * wsh + c32));
#pragma unroll
    for (int tt = 0; tt < 4; ++tt) {
      const f32x4* wp = W1C + 32 * wr + 8 * tt + 4 * h;
      f32x4 hv;
#pragma unroll
      for (int rr = 0; rr < 4; ++rr) {
        f32x4 w = wp[rr];
        float z = fmaf(xv.x, w.x, fmaf(xv.y, w.y, w.z));
        float s = fsigm(z);
        float hh = z * s;
        D1[4 * tt + rr] = s * (1.0f + z - hh);
        hv[rr] = hh;
      }
      storeAct(tt, hv);
    }
  };

  auto g_finish = [&](int step) {
    if (t < 128) {
      float g = GPf[t] + GPf[128 + t] + GPf[256 + t] + GPf[384 + t];
      g = fminf(fmaxf(g, -0.03f), 0.03f);
      float epsv = 10.0f * (1.0f - (float)step / 60.0f);
      float xn = XB[t] + sqrtf(2.0f * epsv) * nz * 0.005f + epsv * g;
      xn = fminf(fmaxf(xn, -2.43f), 3.05f);
      XB[t] = xn;
      if (step == NSTEP - 1) {
        out[(size_t)blk * 128 + t] = xn;
      } else {
        nz = noise[(size_t)(step + 1) * NTOT * 2 + nbase];
      }
    }
  };

#pragma unroll 1
  for (int step = 0; step < NSTEP; ++step) {
    l1_phase();        __syncthreads();
    gemm(0);           __syncthreads();   // z2 (A = W2^T from L2)
    ep_fwd(B2s, D2);   __syncthreads();
    gemm(1);           __syncthreads();   // z3
    ep_fwd(B3s, D3);   __syncthreads();
    gemm(2);           __syncthreads();   // z4
    ep_v4();           __syncthreads();
    gemm(3);           __syncthreads();   // u3 (A = W4 nat)
    ep_bwd(D3);        __syncthreads();
    gemm(4);           __syncthreads();   // u2
    ep_bwd(D2);        __syncthreads();
    gemm(5);           __syncthreads();   // u1
    ep_bwd1();         __syncthreads();   // g partials
    g_finish(step);    __syncthreads();
  }
}

extern "C" void kernel_launch(void* const* d_in, const int* in_sizes, int n_in,
                              void* d_out, int out_size, void* d_ws, size_t ws_size,
                              hipStream_t stream) {
  // inputs: x0,w1,b1,w2,b2,w3,b3,w4,b4,w5,b5,noise
  (void)in_sizes; (void)n_in; (void)out_size; (void)ws_size;
  hipFuncSetAttribute((const void*)ebm_mcmc_kernel,
                      hipFuncAttributeMaxDynamicSharedMemorySize, LDS_TOTAL);
  ebm_prep_kernel<<<6, 256, 0, stream>>>(
      (const float*)d_in[3], (const float*)d_in[5], (const float*)d_in[7],
      (uint16_t*)d_ws);
  ebm_mcmc_kernel<<<NBLK, 512, LDS_TOTAL, stream>>>(
      (const float*)d_in[0], (const float*)d_in[1], (const float*)d_in[2],
      (const float*)d_in[4], (const float*)d_in[6], (const float*)d_in[8],
      (const float*)d_in[9], (const float*)d_in[11], (const uint16_t*)d_ws,
      (float*)d_out);
}